// Round 4
// baseline (2171.180 us; speedup 1.0000x reference)
//
#include <hip/hip_runtime.h>
#include <hip/hip_fp16.h>

#define B_  32
#define L_  2048
#define H_  128
#define H2_ 256
#define V_  32000
#define NT_ (B_*L_)
#define TOKS_PER_BLK 64
#define CH_ 32                 // k-rows per staged chunk in kc_scan

typedef _Float16 h2v __attribute__((ext_vector_type(2)));

__device__ __forceinline__ float fdot2f(h2v a, h2v b, float c) {
#if __has_builtin(__builtin_amdgcn_fdot2)
    return __builtin_amdgcn_fdot2(a, b, c, false);
#else
    return fmaf((float)a[1], (float)b[1], fmaf((float)a[0], (float)b[0], c));
#endif
}

// ---------------- DPP wave-reduce helpers (VALU, no LDS) --------------------
template<int CTRL, int RMASK>
__device__ __forceinline__ float dpp_add(float x) {
    int v = __builtin_amdgcn_update_dpp(0, __float_as_int(x), CTRL, RMASK, 0xf, true);
    return x + __int_as_float(v);
}
__device__ __forceinline__ float wave_sum63(float x) {
    x = dpp_add<0x111, 0xf>(x);   // row_shr:1
    x = dpp_add<0x112, 0xf>(x);   // row_shr:2
    x = dpp_add<0x114, 0xf>(x);   // row_shr:4
    x = dpp_add<0x118, 0xf>(x);   // row_shr:8
    x = dpp_add<0x142, 0xa>(x);   // row_bcast:15
    x = dpp_add<0x143, 0xc>(x);   // row_bcast:31
    return x;
}
__device__ __forceinline__ float wave_allsum(float x) {
    x = wave_sum63(x);
    return __int_as_float(__builtin_amdgcn_readlane(__float_as_int(x), 63));
}
__device__ __forceinline__ float pair_sum(float x) {
    int v = __builtin_amdgcn_update_dpp(0, __float_as_int(x), 0xB1, 0xf, 0xf, true);
    return x + __int_as_float(v);
}

// ---------------------------------------------------------------------------
// Kernel A: embed gather + FF + residual + LayerNorm + k-projection -> k_all
// fp16 dot2 path for FF; kp_w fp32 in regs.
// ---------------------------------------------------------------------------
__global__ __launch_bounds__(256, 2) void ka_ff_ln_kp(
    const int*   __restrict__ seq,   const float* __restrict__ embed_w,
    const float* __restrict__ ff_w1, const float* __restrict__ ff_b1,
    const float* __restrict__ ff_w2, const float* __restrict__ ff_b2,
    const float* __restrict__ ln_g,  const float* __restrict__ ln_b,
    const float* __restrict__ kp_w,  float* __restrict__ k_all)
{
    __shared__ h2v w1p[64][256];       // 64KB: w1p[j2][o] = (W1[o][2j2], W1[o][2j2+1])
    __shared__ float2 h2[128];         // fp32 h (tok0,tok1) for residual
    __shared__ h2v   h16[2][64];       // fp16 h pairs per token
    __shared__ _Float16 y16[2][256];   // fp16 relu output per token
    __shared__ float  p_sh[2][2][128];
    __shared__ float2 hln2[128];
    __shared__ float  red_sh[8];

    const int tid  = threadIdx.x;
    const int half = tid >> 7;
    const int i    = tid & 127;
    const int lane = tid & 63;
    const int wave = tid >> 6;

    for (int idx = tid; idx < 64*256; idx += 256) {
        int o = idx >> 6, j2 = idx & 63;
        float2 ab = *(const float2*)(ff_w1 + o*128 + 2*j2);
        h2v p; p[0] = (_Float16)ab.x; p[1] = (_Float16)ab.y;
        w1p[j2][o] = p;
    }
    // w2 row i, cols [128*half, 128*half+128) as 64 fp16 pairs in regs
    h2v w2r[64];
    {
        const float* src = ff_w2 + (size_t)i*H2_ + half*128;
        #pragma unroll
        for (int q2 = 0; q2 < 64; ++q2) {
            float2 ab = *(const float2*)(src + 2*q2);
            h2v p; p[0] = (_Float16)ab.x; p[1] = (_Float16)ab.y;
            w2r[q2] = p;
        }
    }
    float kreg[64];
    {
        const float* src = kp_w + (size_t)i*H_ + half*64;
        #pragma unroll
        for (int j4 = 0; j4 < 16; ++j4) {
            float4 v = *(const float4*)(src + j4*4);
            kreg[j4*4+0]=v.x; kreg[j4*4+1]=v.y; kreg[j4*4+2]=v.z; kreg[j4*4+3]=v.w;
        }
    }
    const float b1v = ff_b1[tid];
    const float b2v = ff_b2[i];
    const float gv  = ln_g[i];
    const float bv  = ln_b[i];
    __syncthreads();

    const int base = blockIdx.x * TOKS_PER_BLK;
    for (int it = 0; it < TOKS_PER_BLK; it += 2) {
        const int t0 = base + it;
        if (tid < 64) {
            int tok = tid >> 5;
            int l32 = tid & 31;
            int v   = seq[t0 + tok];
            float4 hv = *(const float4*)(embed_w + (size_t)v*H_ + l32*4);
            ((float*)&h2[l32*4+0])[tok] = hv.x;
            ((float*)&h2[l32*4+1])[tok] = hv.y;
            ((float*)&h2[l32*4+2])[tok] = hv.z;
            ((float*)&h2[l32*4+3])[tok] = hv.w;
            h2v pa; pa[0]=(_Float16)hv.x; pa[1]=(_Float16)hv.y;
            h2v pb; pb[0]=(_Float16)hv.z; pb[1]=(_Float16)hv.w;
            h16[tok][l32*2+0] = pa;
            h16[tok][l32*2+1] = pb;
        }
        __syncthreads();                        // B1
        // ---- y1 = relu(W1 h + b1), o = tid, both tokens, fp16 dot2 ----
        float a0 = b1v, a1 = b1v;
        #pragma unroll
        for (int j2 = 0; j2 < 64; ++j2) {
            h2v w = w1p[j2][tid];
            a0 = fdot2f(w, h16[0][j2], a0);
            a1 = fdot2f(w, h16[1][j2], a1);
        }
        y16[0][tid] = (_Float16)fmaxf(a0, 0.f);
        y16[1][tid] = (_Float16)fmaxf(a1, 0.f);
        __syncthreads();                        // B2
        // ---- y2 partial: thread (half,i), cols [128h,128h+128) ----
        float c0 = 0.f, c1 = 0.f;
        #pragma unroll
        for (int q2 = 0; q2 < 64; ++q2) {
            h2v w = w2r[q2];
            c0 = fdot2f(w, *(const h2v*)&y16[0][half*128 + 2*q2], c0);
            c1 = fdot2f(w, *(const h2v*)&y16[1][half*128 + 2*q2], c1);
        }
        p_sh[half][0][i] = c0;
        p_sh[half][1][i] = c1;
        __syncthreads();                        // B3
        float x = ((const float*)&h2[i])[half] + p_sh[0][half][i] + p_sh[1][half][i] + b2v;
        {
            float s = x, s2 = x*x;
            #pragma unroll
            for (int m = 1; m <= 32; m <<= 1) {
                s  += __shfl_xor(s,  m);
                s2 += __shfl_xor(s2, m);
            }
            if (lane == 0) { red_sh[wave*2] = s; red_sh[wave*2+1] = s2; }
        }
        __syncthreads();                        // B4
        float mu  = (red_sh[half*4+0] + red_sh[half*4+2]) * (1.0f/128.0f);
        float ex2 = (red_sh[half*4+1] + red_sh[half*4+3]) * (1.0f/128.0f);
        float var = ex2 - mu*mu;
        float rstd = 1.0f / sqrtf(var + 1e-5f);
        float hln = (x - mu) * rstd * gv + bv;
        ((float*)&hln2[i])[half] = hln;
        __syncthreads();                        // B5
        float k0 = 0.f, k1 = 0.f;
        #pragma unroll
        for (int jj = 0; jj < 64; ++jj) {
            float2 hh = hln2[half*64 + jj];
            k0 = fmaf(kreg[jj], hh.x, k0);
            k1 = fmaf(kreg[jj], hh.y, k1);
        }
        p_sh[half][0][i] = k0;
        p_sh[half][1][i] = k1;
        __syncthreads();                        // B6
        if (tid < 128) {
            k_all[(size_t)t0*H_     + i] = p_sh[0][0][i] + p_sh[1][0][i];
            k_all[(size_t)(t0+1)*H_ + i] = p_sh[0][1][i] + p_sh[1][1][i];
        }
    }
}

// ---------------------------------------------------------------------------
// Kernel C v3: gate-decoupled pipelined scan. 32 blocks x 256 threads.
// Lane-pair layout: lane l of wave w owns row r=w*32+(l>>1), half=l&1.
// Pipeline identity: M_t @ k_{t+1} = M_{t-1}@k_{t+1} + c_t*(k_t . k_{t+1})*err_t
// so the fused [lazy-update + next-Q] 128-FMA block is independent of the
// current gate and issues before the barrier. kappa/nk2 from k data, off-path.
// Bank conflicts: per-half rotated read order (banks 4j vs 4j+16).
// ---------------------------------------------------------------------------
__global__ __launch_bounds__(256, 1) void kc_scan(
    const float* __restrict__ k_all, const float* __restrict__ rp_w,
    const float* __restrict__ rp_b,  float* __restrict__ r_out)
{
    __shared__ __align__(16) float kch[2][CH_*H_];   // 32KB, double-buffered chunks
    __shared__ __align__(16) float red[2][4];
    __shared__ __align__(16) float read_sh[128];
    __shared__ float pr_sh[2][128];

    const int b    = blockIdx.x;
    const int tid  = threadIdx.x;
    const int lane = tid & 63;
    const int wave = tid >> 6;
    const int half = lane & 1;
    const int r    = wave*32 + (lane >> 1);
    const int cbase = half*64;
    const int jrot  = half*4;      // per-half rotation -> conflict-free dual-address reads

    const float* kb = k_all + (size_t)b * (L_*H_);

    float M[64];
    #pragma unroll
    for (int j = 0; j < 64; ++j) M[j] = 0.f;

    // ---- stage chunk 0 ----
    #pragma unroll
    for (int jr = 0; jr < 4; ++jr) {
        float4 v = *(const float4*)(kb + jr*1024 + tid*4);
        *(float4*)&kch[0][jr*1024 + tid*4] = v;
    }
    __syncthreads();

    // ---- pipeline init (row 0) ----
    float2 kqo = *(const float2*)(kch[0] + (lane<<1));
    float nk2_cur = wave_allsum(fmaf(kqo.x, kqo.x, kqo.y*kqo.y));
    float rn_cur  = 1.0f / fmaxf(sqrtf(nk2_cur), 1e-12f);
    float kr_cur  = kch[0][r];
    float Q = 0.f, corr = 0.f, upd = 0.f, errprev = 0.f;
    float4 st[4];

    #pragma unroll 1
    for (int t = 0; t < L_-1; ++t) {
        const int row = t & 31;
        const int buf = (t>>5) & 1;
        const int tp  = (t == 0) ? 0 : t - 1;
        const float* krp = &kch[(tp>>5)&1][(tp&31)*H_];       // k_{t-1}
        const float* krn = &kch[((t+1)>>5)&1][((t+1)&31)*H_]; // k_{t+1}

        // ---- serial head: P_t, err_t, esum ----
        float P   = fmaf(corr, errprev, Q);        // M_{t-1}@k_t, row r
        float err = fmaf(-rn_cur, P, kr_cur);
        float esum = wave_sum63(err*err);
        if (lane == 63) red[t&1][wave] = esum;

        // ---- next-row scalars (off critical path) ----
        float2 kqn = *(const float2*)(krn + (lane<<1));
        float kr_next = krn[r];
        float nk2_next = wave_allsum(fmaf(kqn.x, kqn.x, kqn.y*kqn.y));
        float kap      = wave_allsum(fmaf(kqo.x, kqn.x, kqo.y*kqn.y)); // k_t . k_{t+1}
        float rn_next  = 1.0f / fmaxf(sqrtf(nk2_next), 1e-12f);

        // ---- write staged chunk to LDS (loaded 16 steps ago) ----
        if (row == 17 && t < 2016) {
            float* dst = &kch[buf^1][0];
            #pragma unroll
            for (int jr = 0; jr < 4; ++jr) *(float4*)&dst[jr*1024 + tid*4] = st[jr];
        }

        // ---- fused lazy-update + Q' = M_{t-1}@k_{t+1} (gate-independent) ----
        float q0=0.f, q1=0.f, q2=0.f, q3=0.f;
        #pragma unroll
        for (int j4 = 0; j4 < 16; ++j4) {
            const int off = cbase + (((j4 + jrot) & 15) << 2);
            float4 kp = *(const float4*)(krp + off);
            float4 kn = *(const float4*)(krn + off);
            M[j4*4+0] = fmaf(upd, kp.x, M[j4*4+0]); q0 = fmaf(M[j4*4+0], kn.x, q0);
            M[j4*4+1] = fmaf(upd, kp.y, M[j4*4+1]); q1 = fmaf(M[j4*4+1], kn.y, q1);
            M[j4*4+2] = fmaf(upd, kp.z, M[j4*4+2]); q2 = fmaf(M[j4*4+2], kn.z, q2);
            M[j4*4+3] = fmaf(upd, kp.w, M[j4*4+3]); q3 = fmaf(M[j4*4+3], kn.w, q3);
        }
        float Qn = pair_sum((q0+q1) + (q2+q3));

        __syncthreads();

        // ---- issue next chunk loads AFTER barrier (drained at next barrier) ----
        if (row == 1 && t < 2016) {
            const float* src = kb + (size_t)((t>>5)+1)*(CH_*H_);
            #pragma unroll
            for (int jr = 0; jr < 4; ++jr) st[jr] = *(const float4*)(src + jr*1024 + tid*4);
        }

        // ---- gate ----
        float4 rv = *(const float4*)&red[t&1][0];
        float rsum = (rv.x+rv.y) + (rv.z+rv.w);    // = 2*||err||^2
        float c = (rsum >= 0.98f * nk2_cur) ? 0.05f * rn_cur : 0.0f;

        // ---- rotate pipeline state ----
        corr = c * kap;
        upd  = c * err;
        errprev = err;
        Q = Qn;
        nk2_cur = nk2_next; rn_cur = rn_next;
        kr_cur = kr_next;   kqo = kqn;
    }

    // ---- readout: read[r] = M_{2046}@q = Q + corr*errprev ----
    {
        float rdv = fmaf(corr, errprev, Q);
        if (half == 0) read_sh[r] = rdv;
    }
    __syncthreads();
    // ---- r = read @ rp_w.T + rp_b ----
    {
        const int o  = tid & 127;
        const int hf = tid >> 7;
        float acc = 0.f;
        #pragma unroll
        for (int j4 = 0; j4 < 16; ++j4) {
            float4 wv = *(const float4*)(rp_w + (size_t)o*H_ + hf*64 + j4*4);
            float4 rv = *(const float4*)&read_sh[hf*64 + j4*4];
            acc = fmaf(wv.x, rv.x, acc);
            acc = fmaf(wv.y, rv.y, acc);
            acc = fmaf(wv.z, rv.z, acc);
            acc = fmaf(wv.w, rv.w, acc);
        }
        pr_sh[hf][o] = acc;
    }
    __syncthreads();
    if (tid < 128) r_out[b*H_ + tid] = pr_sh[0][tid] + pr_sh[1][tid] + rp_b[tid];
}

// ---------------------------------------------------------------------------
// Kernel D: out[b,v] = sum_h r[b,h]*out_w[v,h] + out_b[v].
// ---------------------------------------------------------------------------
__global__ __launch_bounds__(256) void kd_out(
    const float* __restrict__ r_in, const float* __restrict__ out_w,
    const float* __restrict__ out_b, float* __restrict__ out)
{
    __shared__ float r_sh[B_ * H_];
    const int tid = threadIdx.x;
    for (int idx = tid; idx < B_*H_; idx += 256) r_sh[idx] = r_in[idx];
    __syncthreads();
    const int v = blockIdx.x * 256 + tid;
    const float* wrow = out_w + (size_t)v * H_;
    float acc[B_];
    #pragma unroll
    for (int bb = 0; bb < B_; ++bb) acc[bb] = 0.f;
    for (int h4 = 0; h4 < H_/4; ++h4) {
        float4 w = *(const float4*)(wrow + h4*4);
        #pragma unroll
        for (int bb = 0; bb < B_; ++bb) {
            const float* rr = &r_sh[bb*H_ + h4*4];
            acc[bb] = fmaf(w.x, rr[0], acc[bb]);
            acc[bb] = fmaf(w.y, rr[1], acc[bb]);
            acc[bb] = fmaf(w.z, rr[2], acc[bb]);
            acc[bb] = fmaf(w.w, rr[3], acc[bb]);
        }
    }
    const float bias = out_b[v];
    #pragma unroll
    for (int bb = 0; bb < B_; ++bb) out[(size_t)bb*V_ + v] = acc[bb] + bias;
}

// ---------------------------------------------------------------------------
extern "C" void kernel_launch(void* const* d_in, const int* in_sizes, int n_in,
                              void* d_out, int out_size, void* d_ws, size_t ws_size,
                              hipStream_t stream)
{
    const int*   seq     = (const int*)  d_in[0];
    const float* embed_w = (const float*)d_in[1];
    const float* ff_w1   = (const float*)d_in[2];
    const float* ff_b1   = (const float*)d_in[3];
    const float* ff_w2   = (const float*)d_in[4];
    const float* ff_b2   = (const float*)d_in[5];
    const float* ln_g    = (const float*)d_in[6];
    const float* ln_b    = (const float*)d_in[7];
    const float* kp_w    = (const float*)d_in[8];
    const float* rp_w    = (const float*)d_in[9];
    const float* rp_b    = (const float*)d_in[10];
    const float* out_w   = (const float*)d_in[11];
    const float* out_b   = (const float*)d_in[12];
    float* out = (float*)d_out;

    float* k_all = (float*)d_ws;
    float* r_buf = k_all + (size_t)NT_ * H_;

    ka_ff_ln_kp<<<dim3(NT_/TOKS_PER_BLK), dim3(256), 0, stream>>>(
        seq, embed_w, ff_w1, ff_b1, ff_w2, ff_b2, ln_g, ln_b, kp_w, k_all);
    kc_scan<<<dim3(B_), dim3(256), 0, stream>>>(k_all, rp_w, rp_b, r_buf);
    kd_out<<<dim3(V_/256), dim3(256), 0, stream>>>(r_buf, out_w, out_b, out);
}

// Round 5
// 1990.544 us; speedup vs baseline: 1.0907x; 1.0907x over previous
//
#include <hip/hip_runtime.h>
#include <hip/hip_fp16.h>

#define B_  32
#define L_  2048
#define H_  128
#define H2_ 256
#define V_  32000
#define NT_ (B_*L_)
#define TOKS_PER_BLK 64
#define CH_ 32                 // k-rows per staged chunk in kc_scan

// ---------------- DPP wave-reduce helpers (VALU, no LDS) --------------------
template<int CTRL, int RMASK>
__device__ __forceinline__ float dpp_add(float x) {
    int v = __builtin_amdgcn_update_dpp(0, __float_as_int(x), CTRL, RMASK, 0xf, true);
    return x + __int_as_float(v);
}
__device__ __forceinline__ float wave_sum63(float x) {
    x = dpp_add<0x111, 0xf>(x);   // row_shr:1
    x = dpp_add<0x112, 0xf>(x);   // row_shr:2
    x = dpp_add<0x114, 0xf>(x);   // row_shr:4
    x = dpp_add<0x118, 0xf>(x);   // row_shr:8
    x = dpp_add<0x142, 0xa>(x);   // row_bcast:15
    x = dpp_add<0x143, 0xc>(x);   // row_bcast:31
    return x;
}
__device__ __forceinline__ float wave_allsum(float x) {
    x = wave_sum63(x);
    return __int_as_float(__builtin_amdgcn_readlane(__float_as_int(x), 63));
}
__device__ __forceinline__ float pair_sum(float x) {
    int v = __builtin_amdgcn_update_dpp(0, __float_as_int(x), 0xB1, 0xf, 0xf, true);
    return x + __int_as_float(v);
}

// ---------------------------------------------------------------------------
// Kernel A (round-3-measured version): embed gather + FF + residual + LN +
// k-projection. fp16 WEIGHTS only (w1 LDS, w2 regs); fp32 activations.
// ---------------------------------------------------------------------------
__global__ __launch_bounds__(256, 2) void ka_ff_ln_kp(
    const int*   __restrict__ seq,   const float* __restrict__ embed_w,
    const float* __restrict__ ff_w1, const float* __restrict__ ff_b1,
    const float* __restrict__ ff_w2, const float* __restrict__ ff_b2,
    const float* __restrict__ ln_g,  const float* __restrict__ ln_b,
    const float* __restrict__ kp_w,  float* __restrict__ k_all)
{
    __shared__ __half2 w1p[64][256];   // 64KB
    __shared__ float2 h2[128];
    __shared__ float2 y12[256];
    __shared__ float  p_sh[2][2][128];
    __shared__ float2 hln2[128];
    __shared__ float  red_sh[8];

    const int tid  = threadIdx.x;
    const int half = tid >> 7;
    const int i    = tid & 127;
    const int lane = tid & 63;
    const int wave = tid >> 6;

    for (int idx = tid; idx < 64*256; idx += 256) {
        int o = idx >> 6, j2 = idx & 63;
        float2 ab = *(const float2*)(ff_w1 + o*128 + 2*j2);
        w1p[j2][o] = __floats2half2_rn(ab.x, ab.y);
    }
    __half2 w2r[64];
    {
        const float* src = ff_w2 + (size_t)i*H2_ + half*128;
        #pragma unroll
        for (int q4 = 0; q4 < 16; ++q4) {
            float4 a = *(const float4*)(src + q4*8);
            float4 b = *(const float4*)(src + q4*8 + 4);
            w2r[q4*4+0] = __floats2half2_rn(a.x, a.y);
            w2r[q4*4+1] = __floats2half2_rn(a.z, a.w);
            w2r[q4*4+2] = __floats2half2_rn(b.x, b.y);
            w2r[q4*4+3] = __floats2half2_rn(b.z, b.w);
        }
    }
    float kreg[64];
    {
        const float* src = kp_w + (size_t)i*H_ + half*64;
        #pragma unroll
        for (int j4 = 0; j4 < 16; ++j4) {
            float4 v = *(const float4*)(src + j4*4);
            kreg[j4*4+0]=v.x; kreg[j4*4+1]=v.y; kreg[j4*4+2]=v.z; kreg[j4*4+3]=v.w;
        }
    }
    const float b1v = ff_b1[tid];
    const float b2v = ff_b2[i];
    const float gv  = ln_g[i];
    const float bv  = ln_b[i];
    __syncthreads();

    const int base = blockIdx.x * TOKS_PER_BLK;
    for (int it = 0; it < TOKS_PER_BLK; it += 2) {
        const int t0 = base + it;
        if (tid < 64) {
            int tok = tid >> 5;
            int l32 = tid & 31;
            int v   = seq[t0 + tok];
            float4 hv = *(const float4*)(embed_w + (size_t)v*H_ + l32*4);
            ((float*)&h2[l32*4+0])[tok] = hv.x;
            ((float*)&h2[l32*4+1])[tok] = hv.y;
            ((float*)&h2[l32*4+2])[tok] = hv.z;
            ((float*)&h2[l32*4+3])[tok] = hv.w;
        }
        __syncthreads();                        // B1
        float a0 = b1v, a1 = b1v;
        #pragma unroll
        for (int j2 = 0; j2 < 64; ++j2) {
            __half2 w = w1p[j2][tid];
            float4 hh = *(const float4*)&h2[2*j2];
            float wl = __low2float(w), wh = __high2float(w);
            a0 = fmaf(wl, hh.x, a0); a0 = fmaf(wh, hh.z, a0);
            a1 = fmaf(wl, hh.y, a1); a1 = fmaf(wh, hh.w, a1);
        }
        y12[tid] = make_float2(fmaxf(a0, 0.f), fmaxf(a1, 0.f));
        __syncthreads();                        // B2
        float c0 = 0.f, c1 = 0.f;
        #pragma unroll
        for (int q = 0; q < 64; ++q) {
            __half2 w = w2r[q];
            float4 yy = *(const float4*)&y12[half*128 + 2*q];
            float wl = __low2float(w), wh = __high2float(w);
            c0 = fmaf(wl, yy.x, c0); c0 = fmaf(wh, yy.z, c0);
            c1 = fmaf(wl, yy.y, c1); c1 = fmaf(wh, yy.w, c1);
        }
        p_sh[half][0][i] = c0;
        p_sh[half][1][i] = c1;
        __syncthreads();                        // B3
        float x = ((const float*)&h2[i])[half] + p_sh[0][half][i] + p_sh[1][half][i] + b2v;
        {
            float s = x, s2 = x*x;
            #pragma unroll
            for (int m = 1; m <= 32; m <<= 1) {
                s  += __shfl_xor(s,  m);
                s2 += __shfl_xor(s2, m);
            }
            if (lane == 0) { red_sh[wave*2] = s; red_sh[wave*2+1] = s2; }
        }
        __syncthreads();                        // B4
        float mu  = (red_sh[half*4+0] + red_sh[half*4+2]) * (1.0f/128.0f);
        float ex2 = (red_sh[half*4+1] + red_sh[half*4+3]) * (1.0f/128.0f);
        float var = ex2 - mu*mu;
        float rstd = 1.0f / sqrtf(var + 1e-5f);
        float hln = (x - mu) * rstd * gv + bv;
        ((float*)&hln2[i])[half] = hln;
        __syncthreads();                        // B5
        float k0 = 0.f, k1 = 0.f;
        #pragma unroll
        for (int jj = 0; jj < 64; ++jj) {
            float2 hh = hln2[half*64 + jj];
            k0 = fmaf(kreg[jj], hh.x, k0);
            k1 = fmaf(kreg[jj], hh.y, k1);
        }
        p_sh[half][0][i] = k0;
        p_sh[half][1][i] = k1;
        __syncthreads();                        // B6
        if (tid < 128) {
            k_all[(size_t)t0*H_     + i] = p_sh[0][0][i] + p_sh[1][0][i];
            k_all[(size_t)(t0+1)*H_ + i] = p_sh[0][1][i] + p_sh[1][1][i];
        }
    }
}

// ---------------------------------------------------------------------------
// Kernel C v4: coupled scan with REGISTER k-pipeline.
// Lane l of wave w owns row r=w*32+(l>>1), half=l&1; M[64] VGPRs.
// KT[64] regs hold k_i; fused loop: read KT (update with k_i), load k_{i+1}
// from LDS (16 b128, 2-addr broadcast+rot, conflict-free), matvec with it,
// overwrite KT. One barrier/step; gate via DPP esum + 4-slot LDS combine;
// k[r] extracted by ds_bpermute from the kq pair (no 32-way-conflict read).
// ---------------------------------------------------------------------------
__global__ __launch_bounds__(256, 1) void kc_scan(
    const float* __restrict__ k_all, const float* __restrict__ rp_w,
    const float* __restrict__ rp_b,  float* __restrict__ r_out)
{
    __shared__ __align__(16) float kch[2][CH_*H_];   // 32KB double-buffered chunks
    __shared__ __align__(16) float red[2][4];
    __shared__ __align__(16) float read_sh[128];
    __shared__ float pr_sh[2][128];

    const int b    = blockIdx.x;
    const int tid  = threadIdx.x;
    const int lane = tid & 63;
    const int wave = tid >> 6;
    const int half = lane & 1;
    const int r    = wave*32 + (lane >> 1);
    const int cbase = half*64;
    const int jrot  = half*4;           // per-half bank rotation
    const int paddr = (r >> 1) << 2;    // bpermute byte addr: source lane r/2

    const float* kb = k_all + (size_t)b * (L_*H_);

    float M[64];
    #pragma unroll
    for (int j = 0; j < 64; ++j) M[j] = 0.f;

    // ---- stage chunk 0 ----
    #pragma unroll
    for (int jr = 0; jr < 4; ++jr) {
        float4 v = *(const float4*)(kb + jr*1024 + tid*4);
        *(float4*)&kch[0][jr*1024 + tid*4] = v;
    }
    __syncthreads();

    // ---- prologue: KT = k_0 (rotated order), state for step 0 ----
    float KT[64];
    #pragma unroll
    for (int j4 = 0; j4 < 16; ++j4) {
        const int off = cbase + (((j4 + jrot) & 15) << 2);
        float4 kk = *(const float4*)(kch[0] + off);
        KT[j4*4+0]=kk.x; KT[j4*4+1]=kk.y; KT[j4*4+2]=kk.z; KT[j4*4+3]=kk.w;
    }
    float nk2, rn, err;
    {
        float2 kq = *(const float2*)(kch[0] + (lane<<1));
        nk2 = wave_allsum(fmaf(kq.x, kq.x, kq.y*kq.y));
        rn  = 1.0f / fmaxf(sqrtf(nk2), 1e-12f);
        float vx = __int_as_float(__builtin_amdgcn_ds_bpermute(paddr, __float_as_int(kq.x)));
        float vy = __int_as_float(__builtin_amdgcn_ds_bpermute(paddr, __float_as_int(kq.y)));
        err = (r & 1) ? vy : vx;                    // err_0 = k_0[r] (M=0)
        float es = wave_sum63(err*err);
        if (lane == 63) red[0][wave] = es;
    }
    __syncthreads();

    float Qn = 0.f;
    float4 st[4];

    #pragma unroll 1
    for (int i = 0; i < L_-1; ++i) {            // i = 0..2046
        const int tn = i + 1;
        const float* krn = &kch[(tn>>5)&1][(tn&31)*H_];

        // ---- gate for step i (red written last iter) ----
        float4 rv = *(const float4*)&red[i&1][0];
        float rsum = (rv.x+rv.y) + (rv.z+rv.w);     // 2*||err_i||^2
        float c   = (rsum >= 0.98f * nk2) ? 0.05f : 0.0f;
        float upd = c * err * rn;

        // ---- chunk staging (register round-trip; tiny) ----
        if ((i & 31) == 1 && i < 2016) {
            const float* src = kb + (size_t)((i>>5)+1)*(CH_*H_);
            #pragma unroll
            for (int jr = 0; jr < 4; ++jr) st[jr] = *(const float4*)(src + jr*1024 + tid*4);
        }
        if ((i & 31) == 17 && i < 2016) {
            float* dst = &kch[((i>>5)&1)^1][0];
            #pragma unroll
            for (int jr = 0; jr < 4; ++jr) *(float4*)&dst[jr*1024 + tid*4] = st[jr];
        }

        // ---- next-row scalars (independent of gate) ----
        float2 kqn = *(const float2*)(krn + (lane<<1));
        float nk2n = wave_allsum(fmaf(kqn.x, kqn.x, kqn.y*kqn.y));
        float rnn  = 1.0f / fmaxf(sqrtf(nk2n), 1e-12f);
        float vx = __int_as_float(__builtin_amdgcn_ds_bpermute(paddr, __float_as_int(kqn.x)));
        float vy = __int_as_float(__builtin_amdgcn_ds_bpermute(paddr, __float_as_int(kqn.y)));
        float krr = (r & 1) ? vy : vx;              // k_{i+1}[r]

        // ---- fused: M += upd*k_i (KT regs); q = M@k_{i+1}; KT <- k_{i+1} ----
        float q0=0.f, q1=0.f, q2=0.f, q3=0.f;
        #pragma unroll
        for (int j4 = 0; j4 < 16; ++j4) {
            const int off = cbase + (((j4 + jrot) & 15) << 2);
            float4 kk = *(const float4*)(krn + off);
            M[j4*4+0] = fmaf(upd, KT[j4*4+0], M[j4*4+0]); q0 = fmaf(M[j4*4+0], kk.x, q0); KT[j4*4+0] = kk.x;
            M[j4*4+1] = fmaf(upd, KT[j4*4+1], M[j4*4+1]); q1 = fmaf(M[j4*4+1], kk.y, q1); KT[j4*4+1] = kk.y;
            M[j4*4+2] = fmaf(upd, KT[j4*4+2], M[j4*4+2]); q2 = fmaf(M[j4*4+2], kk.z, q2); KT[j4*4+2] = kk.z;
            M[j4*4+3] = fmaf(upd, KT[j4*4+3], M[j4*4+3]); q3 = fmaf(M[j4*4+3], kk.w, q3); KT[j4*4+3] = kk.w;
        }
        Qn = pair_sum((q0+q1) + (q2+q3));           // (M_i @ k_{i+1})[r]

        // ---- state for step i+1 ----
        err = fmaf(-rnn, Qn, krr);                  // k[r] - (M@k)[r]*rn
        float es = wave_sum63(err*err);
        if (lane == 63) red[(i+1)&1][wave] = es;
        nk2 = nk2n; rn = rnn;
        __syncthreads();
    }

    // ---- readout: Qn from last iter = (M_2046 @ q)[r] ----
    if (half == 0) read_sh[r] = Qn;
    __syncthreads();
    {
        const int o  = tid & 127;
        const int hf = tid >> 7;
        float acc = 0.f;
        #pragma unroll
        for (int j4 = 0; j4 < 16; ++j4) {
            float4 wv = *(const float4*)(rp_w + (size_t)o*H_ + hf*64 + j4*4);
            float4 rv = *(const float4*)&read_sh[hf*64 + j4*4];
            acc = fmaf(wv.x, rv.x, acc);
            acc = fmaf(wv.y, rv.y, acc);
            acc = fmaf(wv.z, rv.z, acc);
            acc = fmaf(wv.w, rv.w, acc);
        }
        pr_sh[hf][o] = acc;
    }
    __syncthreads();
    if (tid < 128) r_out[b*H_ + tid] = pr_sh[0][tid] + pr_sh[1][tid] + rp_b[tid];
}

// ---------------------------------------------------------------------------
// Kernel D: out[b,v] = sum_h r[b,h]*out_w[v,h] + out_b[v].
// ---------------------------------------------------------------------------
__global__ __launch_bounds__(256) void kd_out(
    const float* __restrict__ r_in, const float* __restrict__ out_w,
    const float* __restrict__ out_b, float* __restrict__ out)
{
    __shared__ float r_sh[B_ * H_];
    const int tid = threadIdx.x;
    for (int idx = tid; idx < B_*H_; idx += 256) r_sh[idx] = r_in[idx];
    __syncthreads();
    const int v = blockIdx.x * 256 + tid;
    const float* wrow = out_w + (size_t)v * H_;
    float acc[B_];
    #pragma unroll
    for (int bb = 0; bb < B_; ++bb) acc[bb] = 0.f;
    for (int h4 = 0; h4 < H_/4; ++h4) {
        float4 w = *(const float4*)(wrow + h4*4);
        #pragma unroll
        for (int bb = 0; bb < B_; ++bb) {
            const float* rr = &r_sh[bb*H_ + h4*4];
            acc[bb] = fmaf(w.x, rr[0], acc[bb]);
            acc[bb] = fmaf(w.y, rr[1], acc[bb]);
            acc[bb] = fmaf(w.z, rr[2], acc[bb]);
            acc[bb] = fmaf(w.w, rr[3], acc[bb]);
        }
    }
    const float bias = out_b[v];
    #pragma unroll
    for (int bb = 0; bb < B_; ++bb) out[(size_t)bb*V_ + v] = acc[bb] + bias;
}

// ---------------------------------------------------------------------------
extern "C" void kernel_launch(void* const* d_in, const int* in_sizes, int n_in,
                              void* d_out, int out_size, void* d_ws, size_t ws_size,
                              hipStream_t stream)
{
    const int*   seq     = (const int*)  d_in[0];
    const float* embed_w = (const float*)d_in[1];
    const float* ff_w1   = (const float*)d_in[2];
    const float* ff_b1   = (const float*)d_in[3];
    const float* ff_w2   = (const float*)d_in[4];
    const float* ff_b2   = (const float*)d_in[5];
    const float* ln_g    = (const float*)d_in[6];
    const float* ln_b    = (const float*)d_in[7];
    const float* kp_w    = (const float*)d_in[8];
    const float* rp_w    = (const float*)d_in[9];
    const float* rp_b    = (const float*)d_in[10];
    const float* out_w   = (const float*)d_in[11];
    const float* out_b   = (const float*)d_in[12];
    float* out = (float*)d_out;

    float* k_all = (float*)d_ws;
    float* r_buf = k_all + (size_t)NT_ * H_;

    ka_ff_ln_kp<<<dim3(NT_/TOKS_PER_BLK), dim3(256), 0, stream>>>(
        seq, embed_w, ff_w1, ff_b1, ff_w2, ff_b2, ln_g, ln_b, kp_w, k_all);
    kc_scan<<<dim3(B_), dim3(256), 0, stream>>>(k_all, rp_w, rp_b, r_buf);
    kd_out<<<dim3(V_/256), dim3(256), 0, stream>>>(r_buf, out_w, out_b, out);
}

// Round 6
// 1931.703 us; speedup vs baseline: 1.1240x; 1.0305x over previous
//
#include <hip/hip_runtime.h>
#include <hip/hip_fp16.h>

#define B_  32
#define L_  2048
#define H_  128
#define H2_ 256
#define V_  32000
#define NT_ (B_*L_)
#define TOKS_PER_BLK 64
#define W_  32                 // scan window
#define NW_ (L_/W_)            // 64 windows

// ---------------- DPP wave-reduce helpers (VALU, no LDS) --------------------
template<int CTRL, int RMASK>
__device__ __forceinline__ float dpp_add(float x) {
    int v = __builtin_amdgcn_update_dpp(0, __float_as_int(x), CTRL, RMASK, 0xf, true);
    return x + __int_as_float(v);
}
__device__ __forceinline__ float wave_sum63(float x) {
    x = dpp_add<0x111, 0xf>(x);   // row_shr:1
    x = dpp_add<0x112, 0xf>(x);   // row_shr:2
    x = dpp_add<0x114, 0xf>(x);   // row_shr:4
    x = dpp_add<0x118, 0xf>(x);   // row_shr:8
    x = dpp_add<0x142, 0xa>(x);   // row_bcast:15
    x = dpp_add<0x143, 0xc>(x);   // row_bcast:31
    return x;
}
__device__ __forceinline__ float wave_allsum(float x) {
    x = wave_sum63(x);
    return __int_as_float(__builtin_amdgcn_readlane(__float_as_int(x), 63));
}
// full sum within each 4-lane quad (all 4 lanes get result)
__device__ __forceinline__ float quad_sum(float x) {
    int v = __builtin_amdgcn_update_dpp(0, __float_as_int(x), 0xB1, 0xf, 0xf, true);
    x += __int_as_float(v);
    v = __builtin_amdgcn_update_dpp(0, __float_as_int(x), 0x4E, 0xf, 0xf, true);
    return x + __int_as_float(v);
}
// sum within each 16-lane DPP row; result lands in lane 15 of the row
__device__ __forceinline__ float sum16_hi(float x) {
    x = dpp_add<0x111, 0xf>(x);
    x = dpp_add<0x112, 0xf>(x);
    x = dpp_add<0x114, 0xf>(x);
    x = dpp_add<0x118, 0xf>(x);
    return x;
}

// ---------------------------------------------------------------------------
// Kernel A (round-3-measured): embed gather + FF + residual + LN + k-proj.
// fp16 WEIGHTS only (w1 LDS, w2 regs); fp32 activations.
// ---------------------------------------------------------------------------
__global__ __launch_bounds__(256, 2) void ka_ff_ln_kp(
    const int*   __restrict__ seq,   const float* __restrict__ embed_w,
    const float* __restrict__ ff_w1, const float* __restrict__ ff_b1,
    const float* __restrict__ ff_w2, const float* __restrict__ ff_b2,
    const float* __restrict__ ln_g,  const float* __restrict__ ln_b,
    const float* __restrict__ kp_w,  float* __restrict__ k_all)
{
    __shared__ __half2 w1p[64][256];   // 64KB
    __shared__ float2 h2[128];
    __shared__ float2 y12[256];
    __shared__ float  p_sh[2][2][128];
    __shared__ float2 hln2[128];
    __shared__ float  red_sh[8];

    const int tid  = threadIdx.x;
    const int half = tid >> 7;
    const int i    = tid & 127;
    const int lane = tid & 63;
    const int wave = tid >> 6;

    for (int idx = tid; idx < 64*256; idx += 256) {
        int o = idx >> 6, j2 = idx & 63;
        float2 ab = *(const float2*)(ff_w1 + o*128 + 2*j2);
        w1p[j2][o] = __floats2half2_rn(ab.x, ab.y);
    }
    __half2 w2r[64];
    {
        const float* src = ff_w2 + (size_t)i*H2_ + half*128;
        #pragma unroll
        for (int q4 = 0; q4 < 16; ++q4) {
            float4 a = *(const float4*)(src + q4*8);
            float4 b = *(const float4*)(src + q4*8 + 4);
            w2r[q4*4+0] = __floats2half2_rn(a.x, a.y);
            w2r[q4*4+1] = __floats2half2_rn(a.z, a.w);
            w2r[q4*4+2] = __floats2half2_rn(b.x, b.y);
            w2r[q4*4+3] = __floats2half2_rn(b.z, b.w);
        }
    }
    float kreg[64];
    {
        const float* src = kp_w + (size_t)i*H_ + half*64;
        #pragma unroll
        for (int j4 = 0; j4 < 16; ++j4) {
            float4 v = *(const float4*)(src + j4*4);
            kreg[j4*4+0]=v.x; kreg[j4*4+1]=v.y; kreg[j4*4+2]=v.z; kreg[j4*4+3]=v.w;
        }
    }
    const float b1v = ff_b1[tid];
    const float b2v = ff_b2[i];
    const float gv  = ln_g[i];
    const float bv  = ln_b[i];
    __syncthreads();

    const int base = blockIdx.x * TOKS_PER_BLK;
    for (int it = 0; it < TOKS_PER_BLK; it += 2) {
        const int t0 = base + it;
        if (tid < 64) {
            int tok = tid >> 5;
            int l32 = tid & 31;
            int v   = seq[t0 + tok];
            float4 hv = *(const float4*)(embed_w + (size_t)v*H_ + l32*4);
            ((float*)&h2[l32*4+0])[tok] = hv.x;
            ((float*)&h2[l32*4+1])[tok] = hv.y;
            ((float*)&h2[l32*4+2])[tok] = hv.z;
            ((float*)&h2[l32*4+3])[tok] = hv.w;
        }
        __syncthreads();                        // B1
        float a0 = b1v, a1 = b1v;
        #pragma unroll
        for (int j2 = 0; j2 < 64; ++j2) {
            __half2 w = w1p[j2][tid];
            float4 hh = *(const float4*)&h2[2*j2];
            float wl = __low2float(w), wh = __high2float(w);
            a0 = fmaf(wl, hh.x, a0); a0 = fmaf(wh, hh.z, a0);
            a1 = fmaf(wl, hh.y, a1); a1 = fmaf(wh, hh.w, a1);
        }
        y12[tid] = make_float2(fmaxf(a0, 0.f), fmaxf(a1, 0.f));
        __syncthreads();                        // B2
        float c0 = 0.f, c1 = 0.f;
        #pragma unroll
        for (int q = 0; q < 64; ++q) {
            __half2 w = w2r[q];
            float4 yy = *(const float4*)&y12[half*128 + 2*q];
            float wl = __low2float(w), wh = __high2float(w);
            c0 = fmaf(wl, yy.x, c0); c0 = fmaf(wh, yy.z, c0);
            c1 = fmaf(wl, yy.y, c1); c1 = fmaf(wh, yy.w, c1);
        }
        p_sh[half][0][i] = c0;
        p_sh[half][1][i] = c1;
        __syncthreads();                        // B3
        float x = ((const float*)&h2[i])[half] + p_sh[0][half][i] + p_sh[1][half][i] + b2v;
        {
            float s = x, s2 = x*x;
            #pragma unroll
            for (int m = 1; m <= 32; m <<= 1) {
                s  += __shfl_xor(s,  m);
                s2 += __shfl_xor(s2, m);
            }
            if (lane == 0) { red_sh[wave*2] = s; red_sh[wave*2+1] = s2; }
        }
        __syncthreads();                        // B4
        float mu  = (red_sh[half*4+0] + red_sh[half*4+2]) * (1.0f/128.0f);
        float ex2 = (red_sh[half*4+1] + red_sh[half*4+3]) * (1.0f/128.0f);
        float var = ex2 - mu*mu;
        float rstd = 1.0f / sqrtf(var + 1e-5f);
        float hln = (x - mu) * rstd * gv + bv;
        ((float*)&hln2[i])[half] = hln;
        __syncthreads();                        // B5
        float k0 = 0.f, k1 = 0.f;
        #pragma unroll
        for (int jj = 0; jj < 64; ++jj) {
            float2 hh = hln2[half*64 + jj];
            k0 = fmaf(kreg[jj], hh.x, k0);
            k1 = fmaf(kreg[jj], hh.y, k1);
        }
        p_sh[half][0][i] = k0;
        p_sh[half][1][i] = k1;
        __syncthreads();                        // B6
        if (tid < 128) {
            k_all[(size_t)t0*H_     + i] = p_sh[0][0][i] + p_sh[1][0][i];
            k_all[(size_t)(t0+1)*H_ + i] = p_sh[0][1][i] + p_sh[1][1][i];
        }
    }
}

// ---------------------------------------------------------------------------
// Kernel C v5: WINDOWED scan (W=32). 32 blocks x 512 threads (8 waves).
// Identity: M_{j-1}@k_j = P_j + sum_{i<j} G[i][j]*esc_i, with
//   P_j = M_ws@k_j (window-start M), G[i][j]=k_i.k_j, esc_i=0.05*c_i*rn_i*err_i.
// Per window: A1 all waves apply prev window's rank-32 update to register M
// (32 floats/lane, row r=tid>>2, col seg s=tid&3, bank-rotated order);
// A2 all waves compute P (quad-split + 2 DPP) and Gram (16-lane groups);
// B wave 0 runs the serial gate recurrence with NO barriers inside (DPP
// reductions; esc in +2-padded LDS). 3 barriers per 32 steps.
// Readout = window-63 j=31 of the same identity (no gate).
// ---------------------------------------------------------------------------
__global__ __launch_bounds__(512, 2) void kc_scan(
    const float* __restrict__ k_all, const float* __restrict__ rp_w,
    const float* __restrict__ rp_b,  float* __restrict__ r_out)
{
    __shared__ __align__(16) float kch[2][W_*H_];    // 32KB double-buffered k
    __shared__ __align__(16) float P_lds[W_][H_];    // 16KB
    __shared__ __align__(16) float G_T[W_][34];      // G_T[j][i] = k_i . k_j
    __shared__ __align__(16) float escT[H_][34];     // scaled err, [row][j]
    __shared__ __align__(16) float read_sh[H_];
    __shared__ float pr_sh[2][H_];

    const int b    = blockIdx.x;
    const int tid  = threadIdx.x;       // 0..511
    const int lane = tid & 63;
    const int wv   = tid >> 6;          // 0..7
    const int r    = tid >> 2;          // row 0..127
    const int s    = tid & 3;           // col segment (32 cols)
    const int cb   = s << 5;
    const int gi   = tid >> 4;          // Gram row 0..31
    const int gc   = (tid & 15) << 3;   // Gram col base (8 cols)

    const float* kb = k_all + (size_t)b * (L_*H_);

    float Mreg[32];                     // M[r][cb + rot(m)] (rotated col order)
    #pragma unroll
    for (int m = 0; m < 32; ++m) Mreg[m] = 0.f;

    // ---- preload window 0 ----
    {
        float4 a = *(const float4*)(kb + tid*8);
        float4 c = *(const float4*)(kb + tid*8 + 4);
        *(float4*)&kch[0][tid*8]     = a;
        *(float4*)&kch[0][tid*8 + 4] = c;
    }
    __syncthreads();

    #pragma unroll 1
    for (int w = 0; w < NW_; ++w) {
        const int buf = w & 1;
        const float* kcur = kch[buf];
        const float* kprv = kch[buf^1];

        // issue global loads for window w+1 early
        float4 st0, st1;
        if (w + 1 < NW_) {
            const float* src = kb + (size_t)(w+1)*(W_*H_) + tid*8;
            st0 = *(const float4*)(src);
            st1 = *(const float4*)(src + 4);
        }

        // ---- A1: M += esc_{w-1,j} (x) k_{w-1,j} ----
        if (w > 0) {
            #pragma unroll
            for (int j2 = 0; j2 < 16; ++j2) {
                float2 e2 = *(const float2*)&escT[r][2*j2];
                const float* ka0 = kprv + (2*j2)*H_ + cb;
                const float* ka1 = kprv + (2*j2+1)*H_ + cb;
                #pragma unroll
                for (int m8 = 0; m8 < 8; ++m8) {
                    const int a = ((m8 + 2*s) & 7) << 2;
                    float4 kv0 = *(const float4*)(ka0 + a);
                    float4 kv1 = *(const float4*)(ka1 + a);
                    Mreg[m8*4+0] = fmaf(e2.x, kv0.x, Mreg[m8*4+0]);
                    Mreg[m8*4+1] = fmaf(e2.x, kv0.y, Mreg[m8*4+1]);
                    Mreg[m8*4+2] = fmaf(e2.x, kv0.z, Mreg[m8*4+2]);
                    Mreg[m8*4+3] = fmaf(e2.x, kv0.w, Mreg[m8*4+3]);
                    Mreg[m8*4+0] = fmaf(e2.y, kv1.x, Mreg[m8*4+0]);
                    Mreg[m8*4+1] = fmaf(e2.y, kv1.y, Mreg[m8*4+1]);
                    Mreg[m8*4+2] = fmaf(e2.y, kv1.z, Mreg[m8*4+2]);
                    Mreg[m8*4+3] = fmaf(e2.y, kv1.w, Mreg[m8*4+3]);
                }
            }
        }
        __syncthreads();   // bar1: A1 reads of kprv/escT done

        // ---- write staged window w+1 into the buffer A1 just released ----
        if (w + 1 < NW_) {
            *(float4*)&kch[buf^1][tid*8]     = st0;
            *(float4*)&kch[buf^1][tid*8 + 4] = st1;
        }

        // ---- A2: P_lds + Gram for window w ----
        {
            float4 kia = *(const float4*)(kcur + gi*H_ + gc);
            float4 kib = *(const float4*)(kcur + gi*H_ + gc + 4);
            #pragma unroll
            for (int j = 0; j < W_; ++j) {
                const float* kj = kcur + j*H_;
                float p0=0.f, p1=0.f, p2=0.f, p3=0.f;
                #pragma unroll
                for (int m8 = 0; m8 < 8; ++m8) {
                    const int a = ((m8 + 2*s) & 7) << 2;
                    float4 kv = *(const float4*)(kj + cb + a);
                    p0 = fmaf(Mreg[m8*4+0], kv.x, p0);
                    p1 = fmaf(Mreg[m8*4+1], kv.y, p1);
                    p2 = fmaf(Mreg[m8*4+2], kv.z, p2);
                    p3 = fmaf(Mreg[m8*4+3], kv.w, p3);
                }
                float p = quad_sum((p0+p1) + (p2+p3));
                if (s == 0) P_lds[j][r] = p;
                // Gram partial: k_gi . k_j over 8 cols
                float4 ga = *(const float4*)(kj + gc);
                float4 gb = *(const float4*)(kj + gc + 4);
                float g0 = kia.x*ga.x + kia.y*ga.y;
                g0 = fmaf(kia.z, ga.z, g0); g0 = fmaf(kia.w, ga.w, g0);
                float g1 = kib.x*gb.x + kib.y*gb.y;
                g1 = fmaf(kib.z, gb.z, g1); g1 = fmaf(kib.w, gb.w, g1);
                float g = sum16_hi(g0 + g1);
                if ((tid & 15) == 15) G_T[j][gi] = g;
            }
        }
        __syncthreads();   // bar2: P, G, staged k visible

        // ---- B: serial gate recurrence, wave 0 only ----
        if (wv == 0) {
            const int last = (w == NW_-1);
            #pragma unroll
            for (int j = 0; j < W_; ++j) {
                float nk2 = G_T[j][j];
                float rn  = 1.0f / fmaxf(sqrtf(nk2), 1e-12f);
                float t0 = P_lds[j][lane];
                float t1 = P_lds[j][lane + 64];
                float k0 = kcur[j*H_ + lane];
                float k1 = kcur[j*H_ + 64 + lane];
                #pragma unroll
                for (int i2 = 0; i2 < ((j+1)>>1); ++i2) {
                    float2 g2 = *(const float2*)&G_T[j][2*i2];
                    float2 ea = *(const float2*)&escT[lane][2*i2];
                    float2 eb = *(const float2*)&escT[lane+64][2*i2];
                    t0 = fmaf(g2.x, ea.x, t0); t1 = fmaf(g2.x, eb.x, t1);
                    if (2*i2+1 < j) {
                        t0 = fmaf(g2.y, ea.y, t0); t1 = fmaf(g2.y, eb.y, t1);
                    }
                }
                if (last && j == W_-1) {
                    read_sh[lane]      = t0;   // M_final @ q
                    read_sh[lane + 64] = t1;
                } else {
                    float e0 = fmaf(-rn, t0, k0);
                    float e1 = fmaf(-rn, t1, k1);
                    float es = wave_allsum(fmaf(e0, e0, e1*e1));
                    float sc = (es >= 0.49f * nk2) ? 0.05f * rn : 0.f;
                    escT[lane][j]      = sc * e0;
                    escT[lane + 64][j] = sc * e1;
                }
            }
        }
        __syncthreads();   // bar3: esc (or read_sh) ready
    }

    // ---- r = read @ rp_w.T + rp_b ----
    if (tid < 256) {
        const int o  = tid & 127;
        const int hf = tid >> 7;
        float acc = 0.f;
        #pragma unroll
        for (int j4 = 0; j4 < 16; ++j4) {
            float4 wvv = *(const float4*)(rp_w + (size_t)o*H_ + hf*64 + j4*4);
            float4 rv  = *(const float4*)&read_sh[hf*64 + j4*4];
            acc = fmaf(wvv.x, rv.x, acc);
            acc = fmaf(wvv.y, rv.y, acc);
            acc = fmaf(wvv.z, rv.z, acc);
            acc = fmaf(wvv.w, rv.w, acc);
        }
        pr_sh[hf][o] = acc;
    }
    __syncthreads();
    if (tid < 128) r_out[b*H_ + tid] = pr_sh[0][tid] + pr_sh[1][tid] + rp_b[tid];
}

// ---------------------------------------------------------------------------
// Kernel D: out[b,v] = sum_h r[b,h]*out_w[v,h] + out_b[v].
// ---------------------------------------------------------------------------
__global__ __launch_bounds__(256) void kd_out(
    const float* __restrict__ r_in, const float* __restrict__ out_w,
    const float* __restrict__ out_b, float* __restrict__ out)
{
    __shared__ float r_sh[B_ * H_];
    const int tid = threadIdx.x;
    for (int idx = tid; idx < B_*H_; idx += 256) r_sh[idx] = r_in[idx];
    __syncthreads();
    const int v = blockIdx.x * 256 + tid;
    const float* wrow = out_w + (size_t)v * H_;
    float acc[B_];
    #pragma unroll
    for (int bb = 0; bb < B_; ++bb) acc[bb] = 0.f;
    for (int h4 = 0; h4 < H_/4; ++h4) {
        float4 w = *(const float4*)(wrow + h4*4);
        #pragma unroll
        for (int bb = 0; bb < B_; ++bb) {
            const float* rr = &r_sh[bb*H_ + h4*4];
            acc[bb] = fmaf(w.x, rr[0], acc[bb]);
            acc[bb] = fmaf(w.y, rr[1], acc[bb]);
            acc[bb] = fmaf(w.z, rr[2], acc[bb]);
            acc[bb] = fmaf(w.w, rr[3], acc[bb]);
        }
    }
    const float bias = out_b[v];
    #pragma unroll
    for (int bb = 0; bb < B_; ++bb) out[(size_t)bb*V_ + v] = acc[bb] + bias;
}

// ---------------------------------------------------------------------------
extern "C" void kernel_launch(void* const* d_in, const int* in_sizes, int n_in,
                              void* d_out, int out_size, void* d_ws, size_t ws_size,
                              hipStream_t stream)
{
    const int*   seq     = (const int*)  d_in[0];
    const float* embed_w = (const float*)d_in[1];
    const float* ff_w1   = (const float*)d_in[2];
    const float* ff_b1   = (const float*)d_in[3];
    const float* ff_w2   = (const float*)d_in[4];
    const float* ff_b2   = (const float*)d_in[5];
    const float* ln_g    = (const float*)d_in[6];
    const float* ln_b    = (const float*)d_in[7];
    const float* kp_w    = (const float*)d_in[8];
    const float* rp_w    = (const float*)d_in[9];
    const float* rp_b    = (const float*)d_in[10];
    const float* out_w   = (const float*)d_in[11];
    const float* out_b   = (const float*)d_in[12];
    float* out = (float*)d_out;

    float* k_all = (float*)d_ws;
    float* r_buf = k_all + (size_t)NT_ * H_;

    ka_ff_ln_kp<<<dim3(NT_/TOKS_PER_BLK), dim3(256), 0, stream>>>(
        seq, embed_w, ff_w1, ff_b1, ff_w2, ff_b2, ln_g, ln_b, kp_w, k_all);
    kc_scan<<<dim3(B_), dim3(512), 0, stream>>>(k_all, rp_w, rp_b, r_buf);
    kd_out<<<dim3(V_/256), dim3(256), 0, stream>>>(r_buf, out_w, out_b, out);
}

// Round 7
// 1636.555 us; speedup vs baseline: 1.3267x; 1.1803x over previous
//
#include <hip/hip_runtime.h>
#include <hip/hip_fp16.h>

#define B_  32
#define L_  2048
#define H_  128
#define H2_ 256
#define V_  32000
#define NT_ (B_*L_)
#define TOKS_PER_BLK 64
#define W_  32                 // scan window
#define NW_ (L_/W_)            // 64 windows
#define KROW 132               // padded k-row stride (132 % 32 == 4)

// ---------------- DPP wave-reduce helpers (VALU, no LDS) --------------------
template<int CTRL, int RMASK>
__device__ __forceinline__ float dpp_add(float x) {
    int v = __builtin_amdgcn_update_dpp(0, __float_as_int(x), CTRL, RMASK, 0xf, true);
    return x + __int_as_float(v);
}
__device__ __forceinline__ float wave_sum63(float x) {
    x = dpp_add<0x111, 0xf>(x);   // row_shr:1
    x = dpp_add<0x112, 0xf>(x);   // row_shr:2
    x = dpp_add<0x114, 0xf>(x);   // row_shr:4
    x = dpp_add<0x118, 0xf>(x);   // row_shr:8
    x = dpp_add<0x142, 0xa>(x);   // row_bcast:15
    x = dpp_add<0x143, 0xc>(x);   // row_bcast:31
    return x;
}
__device__ __forceinline__ float wave_allsum(float x) {
    x = wave_sum63(x);
    return __int_as_float(__builtin_amdgcn_readlane(__float_as_int(x), 63));
}
// sum within each 16-lane DPP row; result valid in lane 15 of each row
__device__ __forceinline__ float sum16_hi(float x) {
    x = dpp_add<0x111, 0xf>(x);
    x = dpp_add<0x112, 0xf>(x);
    x = dpp_add<0x114, 0xf>(x);
    x = dpp_add<0x118, 0xf>(x);
    return x;
}

// ---------------------------------------------------------------------------
// Kernel A (round-3-measured): embed gather + FF + residual + LN + k-proj.
// fp16 WEIGHTS only (w1 LDS, w2 regs); fp32 activations. Unchanged.
// ---------------------------------------------------------------------------
__global__ __launch_bounds__(256, 2) void ka_ff_ln_kp(
    const int*   __restrict__ seq,   const float* __restrict__ embed_w,
    const float* __restrict__ ff_w1, const float* __restrict__ ff_b1,
    const float* __restrict__ ff_w2, const float* __restrict__ ff_b2,
    const float* __restrict__ ln_g,  const float* __restrict__ ln_b,
    const float* __restrict__ kp_w,  float* __restrict__ k_all)
{
    __shared__ __half2 w1p[64][256];   // 64KB
    __shared__ float2 h2[128];
    __shared__ float2 y12[256];
    __shared__ float  p_sh[2][2][128];
    __shared__ float2 hln2[128];
    __shared__ float  red_sh[8];

    const int tid  = threadIdx.x;
    const int half = tid >> 7;
    const int i    = tid & 127;
    const int lane = tid & 63;
    const int wave = tid >> 6;

    for (int idx = tid; idx < 64*256; idx += 256) {
        int o = idx >> 6, j2 = idx & 63;
        float2 ab = *(const float2*)(ff_w1 + o*128 + 2*j2);
        w1p[j2][o] = __floats2half2_rn(ab.x, ab.y);
    }
    __half2 w2r[64];
    {
        const float* src = ff_w2 + (size_t)i*H2_ + half*128;
        #pragma unroll
        for (int q4 = 0; q4 < 16; ++q4) {
            float4 a = *(const float4*)(src + q4*8);
            float4 b = *(const float4*)(src + q4*8 + 4);
            w2r[q4*4+0] = __floats2half2_rn(a.x, a.y);
            w2r[q4*4+1] = __floats2half2_rn(a.z, a.w);
            w2r[q4*4+2] = __floats2half2_rn(b.x, b.y);
            w2r[q4*4+3] = __floats2half2_rn(b.z, b.w);
        }
    }
    float kreg[64];
    {
        const float* src = kp_w + (size_t)i*H_ + half*64;
        #pragma unroll
        for (int j4 = 0; j4 < 16; ++j4) {
            float4 v = *(const float4*)(src + j4*4);
            kreg[j4*4+0]=v.x; kreg[j4*4+1]=v.y; kreg[j4*4+2]=v.z; kreg[j4*4+3]=v.w;
        }
    }
    const float b1v = ff_b1[tid];
    const float b2v = ff_b2[i];
    const float gv  = ln_g[i];
    const float bv  = ln_b[i];
    __syncthreads();

    const int base = blockIdx.x * TOKS_PER_BLK;
    for (int it = 0; it < TOKS_PER_BLK; it += 2) {
        const int t0 = base + it;
        if (tid < 64) {
            int tok = tid >> 5;
            int l32 = tid & 31;
            int v   = seq[t0 + tok];
            float4 hv = *(const float4*)(embed_w + (size_t)v*H_ + l32*4);
            ((float*)&h2[l32*4+0])[tok] = hv.x;
            ((float*)&h2[l32*4+1])[tok] = hv.y;
            ((float*)&h2[l32*4+2])[tok] = hv.z;
            ((float*)&h2[l32*4+3])[tok] = hv.w;
        }
        __syncthreads();
        float a0 = b1v, a1 = b1v;
        #pragma unroll
        for (int j2 = 0; j2 < 64; ++j2) {
            __half2 w = w1p[j2][tid];
            float4 hh = *(const float4*)&h2[2*j2];
            float wl = __low2float(w), wh = __high2float(w);
            a0 = fmaf(wl, hh.x, a0); a0 = fmaf(wh, hh.z, a0);
            a1 = fmaf(wl, hh.y, a1); a1 = fmaf(wh, hh.w, a1);
        }
        y12[tid] = make_float2(fmaxf(a0, 0.f), fmaxf(a1, 0.f));
        __syncthreads();
        float c0 = 0.f, c1 = 0.f;
        #pragma unroll
        for (int q = 0; q < 64; ++q) {
            __half2 w = w2r[q];
            float4 yy = *(const float4*)&y12[half*128 + 2*q];
            float wl = __low2float(w), wh = __high2float(w);
            c0 = fmaf(wl, yy.x, c0); c0 = fmaf(wh, yy.z, c0);
            c1 = fmaf(wl, yy.y, c1); c1 = fmaf(wh, yy.w, c1);
        }
        p_sh[half][0][i] = c0;
        p_sh[half][1][i] = c1;
        __syncthreads();
        float x = ((const float*)&h2[i])[half] + p_sh[0][half][i] + p_sh[1][half][i] + b2v;
        {
            float s = x, s2 = x*x;
            #pragma unroll
            for (int m = 1; m <= 32; m <<= 1) {
                s  += __shfl_xor(s,  m);
                s2 += __shfl_xor(s2, m);
            }
            if (lane == 0) { red_sh[wave*2] = s; red_sh[wave*2+1] = s2; }
        }
        __syncthreads();
        float mu  = (red_sh[half*4+0] + red_sh[half*4+2]) * (1.0f/128.0f);
        float ex2 = (red_sh[half*4+1] + red_sh[half*4+3]) * (1.0f/128.0f);
        float var = ex2 - mu*mu;
        float rstd = 1.0f / sqrtf(var + 1e-5f);
        float hln = (x - mu) * rstd * gv + bv;
        ((float*)&hln2[i])[half] = hln;
        __syncthreads();
        float k0 = 0.f, k1 = 0.f;
        #pragma unroll
        for (int jj = 0; jj < 64; ++jj) {
            float2 hh = hln2[half*64 + jj];
            k0 = fmaf(kreg[jj], hh.x, k0);
            k1 = fmaf(kreg[jj], hh.y, k1);
        }
        p_sh[half][0][i] = k0;
        p_sh[half][1][i] = k1;
        __syncthreads();
        if (tid < 128) {
            k_all[(size_t)t0*H_     + i] = p_sh[0][0][i] + p_sh[1][0][i];
            k_all[(size_t)(t0+1)*H_ + i] = p_sh[0][1][i] + p_sh[1][1][i];
        }
    }
}

// ---------------------------------------------------------------------------
// Kernel C v6: windowed scan, 32 blocks x 1024 threads (16 waves, 4/SIMD).
// Thread (ct=tid&15, rt=tid>>4) owns M rows {2rt,2rt+1} x cols {8ct..8ct+7}.
// Per window: A1 rank-32 M update (3 LDS + 16 FMA per j); A2 P=M@k_j
// (2 LDS + 16 FMA + 8 DPP per j) -> P_lds; B on wave 0: fully-unrolled
// register recurrence (esc in e0[]/e1[] regs, Gram via v_readlane) -- no LDS
// on the serial chain; waves 1-8 compute Gram(w+1) concurrently with B(w).
// k rows padded to 132 floats to break row-aligned bank conflicts.
// ---------------------------------------------------------------------------
__global__ __launch_bounds__(1024, 4) void kc_scan(
    const float* __restrict__ k_all, const float* __restrict__ rp_w,
    const float* __restrict__ rp_b,  float* __restrict__ r_out)
{
    __shared__ __align__(16) float kch[2][W_*KROW];   // ~33.8KB
    __shared__ __align__(16) float P_lds[W_][H_];     // 16KB
    __shared__ __align__(16) float escT[W_][H_];      // 16KB
    __shared__ __align__(16) float G_lds[2][64][16];  // 8KB [i+32*(j&1)][j>>1]
    __shared__ __align__(16) float read_sh[H_];
    __shared__ float pr_sh[2][H_];

    const int tid  = threadIdx.x;       // 0..1023
    const int lane = tid & 63;
    const int wv   = tid >> 6;          // 0..15
    const int ct   = tid & 15;          // col group (8 cols)
    const int rt   = tid >> 4;          // 0..63 -> rows 2rt, 2rt+1
    const int cb   = ct << 3;
    const int srow = tid >> 5;          // staging row 0..31
    const int scol = (tid & 31) << 2;   // staging col

    const float* kb = k_all + (size_t)blockIdx.x * (L_*H_);

    float M0[8], M1[8];
    #pragma unroll
    for (int c = 0; c < 8; ++c) { M0[c] = 0.f; M1[c] = 0.f; }

    // ---- preload window 0 (padded layout) ----
    {
        float4 v = *(const float4*)(kb + tid*4);
        *(float4*)&kch[0][srow*KROW + scol] = v;
    }
    __syncthreads();

    // ---- prologue: Gram(0) by waves 1..8 ----
    if (wv >= 1 && wv <= 8) {
        const int p0i = (wv-1)*128 + lane*2;
        const int gi  = p0i >> 5;
        const int gj0 = p0i & 31;                    // even
        const float* ki  = &kch[0][gi*KROW];
        const float* kj0 = &kch[0][gj0*KROW];
        const float* kj1 = &kch[0][(gj0+1)*KROW];
        float d00=0,d01=0,d02=0,d03=0, d10=0,d11=0,d12=0,d13=0;
        #pragma unroll 8
        for (int c4 = 0; c4 < 32; ++c4) {
            float4 x = *(const float4*)(ki  + c4*4);
            float4 y = *(const float4*)(kj0 + c4*4);
            float4 z = *(const float4*)(kj1 + c4*4);
            d00=fmaf(x.x,y.x,d00); d01=fmaf(x.y,y.y,d01);
            d02=fmaf(x.z,y.z,d02); d03=fmaf(x.w,y.w,d03);
            d10=fmaf(x.x,z.x,d10); d11=fmaf(x.y,z.y,d11);
            d12=fmaf(x.z,z.z,d12); d13=fmaf(x.w,z.w,d13);
        }
        G_lds[0][gi     ][gj0>>1] = (d00+d01)+(d02+d03);  // gj even
        G_lds[0][gi + 32][gj0>>1] = (d10+d11)+(d12+d13);  // gj odd
    }
    __syncthreads();

    #pragma unroll 1
    for (int w = 0; w < NW_; ++w) {
        const int buf = w & 1;
        const float* kcur = &kch[buf][0];
        const float* kprv = &kch[buf^1][0];
        const bool hn = (w + 1 < NW_);
        float4 stg;
        if (hn) stg = *(const float4*)(kb + (size_t)(w+1)*(W_*H_) + tid*4);

        // ---- A1: M += esc_{w-1,j} (x) k_{w-1,j} ----
        if (w > 0) {
            #pragma unroll 8
            for (int j = 0; j < W_; ++j) {
                float2 e2 = *(const float2*)&escT[j][2*rt];
                const float* kr = kprv + j*KROW + cb;
                float4 a  = *(const float4*)(kr);
                float4 b2 = *(const float4*)(kr + 4);
                M0[0]=fmaf(e2.x,a.x,M0[0]);  M0[1]=fmaf(e2.x,a.y,M0[1]);
                M0[2]=fmaf(e2.x,a.z,M0[2]);  M0[3]=fmaf(e2.x,a.w,M0[3]);
                M0[4]=fmaf(e2.x,b2.x,M0[4]); M0[5]=fmaf(e2.x,b2.y,M0[5]);
                M0[6]=fmaf(e2.x,b2.z,M0[6]); M0[7]=fmaf(e2.x,b2.w,M0[7]);
                M1[0]=fmaf(e2.y,a.x,M1[0]);  M1[1]=fmaf(e2.y,a.y,M1[1]);
                M1[2]=fmaf(e2.y,a.z,M1[2]);  M1[3]=fmaf(e2.y,a.w,M1[3]);
                M1[4]=fmaf(e2.y,b2.x,M1[4]); M1[5]=fmaf(e2.y,b2.y,M1[5]);
                M1[6]=fmaf(e2.y,b2.z,M1[6]); M1[7]=fmaf(e2.y,b2.w,M1[7]);
            }
        }
        __syncthreads();                            // bar1
        if (hn) *(float4*)&kch[buf^1][srow*KROW + scol] = stg;

        // ---- A2: P_j = M @ k_j ----
        #pragma unroll 8
        for (int j = 0; j < W_; ++j) {
            const float* kr = kcur + j*KROW + cb;
            float4 a  = *(const float4*)(kr);
            float4 b2 = *(const float4*)(kr + 4);
            float p0 = M0[0]*a.x;
            p0=fmaf(M0[1],a.y,p0);  p0=fmaf(M0[2],a.z,p0);  p0=fmaf(M0[3],a.w,p0);
            p0=fmaf(M0[4],b2.x,p0); p0=fmaf(M0[5],b2.y,p0);
            p0=fmaf(M0[6],b2.z,p0); p0=fmaf(M0[7],b2.w,p0);
            float p1 = M1[0]*a.x;
            p1=fmaf(M1[1],a.y,p1);  p1=fmaf(M1[2],a.z,p1);  p1=fmaf(M1[3],a.w,p1);
            p1=fmaf(M1[4],b2.x,p1); p1=fmaf(M1[5],b2.y,p1);
            p1=fmaf(M1[6],b2.z,p1); p1=fmaf(M1[7],b2.w,p1);
            p0 = sum16_hi(p0);
            p1 = sum16_hi(p1);
            if (ct == 15) *(float2*)&P_lds[j][2*rt] = make_float2(p0, p1);
        }
        __syncthreads();                            // bar2

        if (wv == 0) {
            // ---- B: serial gate recurrence, fully in registers ----
            float Grf[16];
            #pragma unroll
            for (int p = 0; p < 4; ++p) {
                float4 g4 = *(const float4*)&G_lds[buf][lane][4*p];
                Grf[4*p+0]=g4.x; Grf[4*p+1]=g4.y; Grf[4*p+2]=g4.z; Grf[4*p+3]=g4.w;
            }
            float e0[W_], e1[W_];
            const bool lastw = (w == NW_-1);
            #pragma unroll
            for (int j = 0; j < W_; ++j) {
                float t0 = P_lds[j][lane];
                float t1 = P_lds[j][lane + 64];
                #pragma unroll
                for (int i = 0; i < j; ++i) {
                    float g = __int_as_float(__builtin_amdgcn_readlane(
                        __float_as_int(Grf[j>>1]), i + ((j&1)<<5)));
                    t0 = fmaf(g, e0[i], t0);
                    t1 = fmaf(g, e1[i], t1);
                }
                float nk2 = __int_as_float(__builtin_amdgcn_readlane(
                        __float_as_int(Grf[j>>1]), j + ((j&1)<<5)));
                if (lastw && j == W_-1) {
                    read_sh[lane]      = t0;        // (M_final @ q)[row]
                    read_sh[lane + 64] = t1;
                } else {
                    float rn  = 1.0f / fmaxf(sqrtf(nk2), 1e-12f);
                    float k0  = kcur[j*KROW + lane];
                    float k1  = kcur[j*KROW + 64 + lane];
                    float ev0 = fmaf(-rn, t0, k0);
                    float ev1 = fmaf(-rn, t1, k1);
                    float es  = wave_allsum(fmaf(ev0, ev0, ev1*ev1));
                    float sc  = (es >= 0.49f * nk2) ? 0.05f * rn : 0.f;
                    e0[j] = sc * ev0;
                    e1[j] = sc * ev1;
                    escT[j][lane]      = e0[j];
                    escT[j][lane + 64] = e1[j];
                }
            }
        } else if (wv <= 8 && hn) {
            // ---- Gram(w+1), concurrent with B(w) ----
            const float* kt = &kch[buf^1][0];
            const int p0i = (wv-1)*128 + lane*2;
            const int gi  = p0i >> 5;
            const int gj0 = p0i & 31;
            const float* ki  = kt + gi*KROW;
            const float* kj0 = kt + gj0*KROW;
            const float* kj1 = kt + (gj0+1)*KROW;
            float d00=0,d01=0,d02=0,d03=0, d10=0,d11=0,d12=0,d13=0;
            #pragma unroll 8
            for (int c4 = 0; c4 < 32; ++c4) {
                float4 x = *(const float4*)(ki  + c4*4);
                float4 y = *(const float4*)(kj0 + c4*4);
                float4 z = *(const float4*)(kj1 + c4*4);
                d00=fmaf(x.x,y.x,d00); d01=fmaf(x.y,y.y,d01);
                d02=fmaf(x.z,y.z,d02); d03=fmaf(x.w,y.w,d03);
                d10=fmaf(x.x,z.x,d10); d11=fmaf(x.y,z.y,d11);
                d12=fmaf(x.z,z.z,d12); d13=fmaf(x.w,z.w,d13);
            }
            G_lds[buf^1][gi     ][gj0>>1] = (d00+d01)+(d02+d03);
            G_lds[buf^1][gi + 32][gj0>>1] = (d10+d11)+(d12+d13);
        }
        __syncthreads();                            // bar3
    }

    // ---- r = read @ rp_w.T + rp_b ----
    if (tid < 256) {
        const int o  = tid & 127;
        const int hf = tid >> 7;
        float acc = 0.f;
        #pragma unroll
        for (int j4 = 0; j4 < 16; ++j4) {
            float4 wvv = *(const float4*)(rp_w + (size_t)o*H_ + hf*64 + j4*4);
            float4 rv  = *(const float4*)&read_sh[hf*64 + j4*4];
            acc = fmaf(wvv.x, rv.x, acc);
            acc = fmaf(wvv.y, rv.y, acc);
            acc = fmaf(wvv.z, rv.z, acc);
            acc = fmaf(wvv.w, rv.w, acc);
        }
        pr_sh[hf][o] = acc;
    }
    __syncthreads();
    if (tid < 128) r_out[blockIdx.x*H_ + tid] = pr_sh[0][tid] + pr_sh[1][tid] + rp_b[tid];
}

// ---------------------------------------------------------------------------
// Kernel D: out[b,v] = sum_h r[b,h]*out_w[v,h] + out_b[v].
// ---------------------------------------------------------------------------
__global__ __launch_bounds__(256) void kd_out(
    const float* __restrict__ r_in, const float* __restrict__ out_w,
    const float* __restrict__ out_b, float* __restrict__ out)
{
    __shared__ float r_sh[B_ * H_];
    const int tid = threadIdx.x;
    for (int idx = tid; idx < B_*H_; idx += 256) r_sh[idx] = r_in[idx];
    __syncthreads();
    const int v = blockIdx.x * 256 + tid;
    const float* wrow = out_w + (size_t)v * H_;
    float acc[B_];
    #pragma unroll
    for (int bb = 0; bb < B_; ++bb) acc[bb] = 0.f;
    for (int h4 = 0; h4 < H_/4; ++h4) {
        float4 w = *(const float4*)(wrow + h4*4);
        #pragma unroll
        for (int bb = 0; bb < B_; ++bb) {
            const float* rr = &r_sh[bb*H_ + h4*4];
            acc[bb] = fmaf(w.x, rr[0], acc[bb]);
            acc[bb] = fmaf(w.y, rr[1], acc[bb]);
            acc[bb] = fmaf(w.z, rr[2], acc[bb]);
            acc[bb] = fmaf(w.w, rr[3], acc[bb]);
        }
    }
    const float bias = out_b[v];
    #pragma unroll
    for (int bb = 0; bb < B_; ++bb) out[(size_t)bb*V_ + v] = acc[bb] + bias;
}

// ---------------------------------------------------------------------------
extern "C" void kernel_launch(void* const* d_in, const int* in_sizes, int n_in,
                              void* d_out, int out_size, void* d_ws, size_t ws_size,
                              hipStream_t stream)
{
    const int*   seq     = (const int*)  d_in[0];
    const float* embed_w = (const float*)d_in[1];
    const float* ff_w1   = (const float*)d_in[2];
    const float* ff_b1   = (const float*)d_in[3];
    const float* ff_w2   = (const float*)d_in[4];
    const float* ff_b2   = (const float*)d_in[5];
    const float* ln_g    = (const float*)d_in[6];
    const float* ln_b    = (const float*)d_in[7];
    const float* kp_w    = (const float*)d_in[8];
    const float* rp_w    = (const float*)d_in[9];
    const float* rp_b    = (const float*)d_in[10];
    const float* out_w   = (const float*)d_in[11];
    const float* out_b   = (const float*)d_in[12];
    float* out = (float*)d_out;

    float* k_all = (float*)d_ws;
    float* r_buf = k_all + (size_t)NT_ * H_;

    ka_ff_ln_kp<<<dim3(NT_/TOKS_PER_BLK), dim3(256), 0, stream>>>(
        seq, embed_w, ff_w1, ff_b1, ff_w2, ff_b2, ln_g, ln_b, kp_w, k_all);
    kc_scan<<<dim3(B_), dim3(1024), 0, stream>>>(k_all, rp_w, rp_b, r_buf);
    kd_out<<<dim3(V_/256), dim3(256), 0, stream>>>(r_buf, out_w, out_b, out);
}